// Round 1
// baseline (255.877 us; speedup 1.0000x reference)
//
#include <hip/hip_runtime.h>

// GCN block: h1 = ReLU(Agg(x@W1)+b1); h2 = ReLU(Agg(h1@W2)+b2); out = BN(h2)
// R16: latency-attack on the shared gather (agg_node_f, used by both
// k_agg_gemm and k_agg_stats — the two longest kernels):
//  (a) masked full-width iterations: always 4 gathers/iter, tail edges are
//      cndmask'd to bf16-zero (kills the serial 1-edge remainder chain);
//  (b) slot-index software pipeline: next iteration's 4 bucket slots load
//      while current gathers are in flight (hides slot->gather chain).
// Mean node: ~3 serialized chain-steps -> ~2 pipelined gather-steps.

#define D 128
#define CAP 96   // max in-degree capacity; E/N=12 mean, Poisson tail << 96

typedef __attribute__((ext_vector_type(8))) short bf16x8;
typedef __attribute__((ext_vector_type(4))) float f32x4;

__device__ inline float2 bf2x2(unsigned u) {
    float2 r;
    r.x = __uint_as_float(u << 16);
    r.y = __uint_as_float(u & 0xffff0000u);
    return r;
}
__device__ inline unsigned short f2bf(float f) {
    unsigned u = __float_as_uint(f);
    u += 0x7fffu + ((u >> 16) & 1u);   // round-to-nearest-even
    return (unsigned short)(u >> 16);
}

// ------- fused histogram+fill: one atomic per edge; + W transpose-convert -------
__global__ void k_histfill(const int* __restrict__ row, const int* __restrict__ col,
                           int* __restrict__ cnt, int* __restrict__ bucket, int E,
                           const float* __restrict__ W1, const float* __restrict__ W2,
                           unsigned short* __restrict__ Wt1,
                           unsigned short* __restrict__ Wt2) {
    int e = blockIdx.x * blockDim.x + threadIdx.x;
    if (e < E) {
        int c = col[e];
        int slot = atomicAdd(&cnt[c], 1);
        if (slot < CAP) bucket[(size_t)c * CAP + slot] = row[e];
    }
    if (blockIdx.x < D) {
        int k = blockIdx.x;
        int t = threadIdx.x;
        if (t < D) Wt1[t * D + k] = f2bf(W1[k * D + t]);
        else       Wt2[(t - D) * D + k] = f2bf(W2[k * D + (t - D)]);
    }
}

// ------ 16-wave GEMM compute: wave w -> m-tile w>>1, n-half w&1 (4 n-tiles) ------
__device__ inline void gemm_compute16(const unsigned short* Xs, const unsigned short* Ws,
                                      const int* __restrict__ cnt,
                                      unsigned short* __restrict__ out, int n, int row0) {
    int tid = threadIdx.x;
    int w = tid >> 6;          // 0..15
    int wm = w >> 1;           // m-tile 0..7
    int wn = w & 1;            // n-half 0..1
    int lane = tid & 63;
    int m16 = lane & 15;
    int quad = lane >> 4;

    f32x4 acc[4];
#pragma unroll
    for (int u = 0; u < 4; u++) acc[u] = (f32x4){0.f, 0.f, 0.f, 0.f};

#pragma unroll
    for (int kc = 0; kc < 4; kc++) {
        bf16x8 a = *(const bf16x8*)&Xs[(wm * 16 + m16) * 136 + kc * 32 + quad * 8];
        bf16x8 b[4];
#pragma unroll
        for (int u = 0; u < 4; u++)
            b[u] = *(const bf16x8*)&Ws[((wn * 4 + u) * 16 + m16) * 136 + kc * 32 + quad * 8];
#pragma unroll
        for (int u = 0; u < 4; u++)
            acc[u] = __builtin_amdgcn_mfma_f32_16x16x32_bf16(a, b[u], acc[u], 0, 0, 0);
    }

    int rbase = row0 + wm * 16 + quad * 4;
#pragma unroll
    for (int i = 0; i < 4; i++) {
        int r = rbase + i;
        if (r < n) {
            float sc = rsqrtf((float)cnt[r] + 1.0f);
#pragma unroll
            for (int u = 0; u < 4; u++)
                out[(size_t)r * D + (wn * 4 + u) * 16 + m16] = f2bf(acc[u][i] * sc);
        }
    }
}

// -- GEMM1 (1024 thr, 16 waves): out[r] = bf16((X @ W)[r] * rsqrt(cnt[r]+1)) --
__global__ __launch_bounds__(1024) void k_gemm1(
        const float* __restrict__ Xf, const unsigned short* __restrict__ Wt,
        const int* __restrict__ cnt, unsigned short* __restrict__ out, int n) {
    __shared__ unsigned short Xs[128 * 136];   // +8 pad: 2-way banks (free)
    __shared__ unsigned short Ws[128 * 136];
    int tid = threadIdx.x;
    int row0 = blockIdx.x * 128;

#pragma unroll
    for (int i = 0; i < 2; i++) {
        int c = tid + 1024 * i;
        int r = c >> 4;
        int kc = (c & 15) * 8;
        float4 va = {0.f, 0.f, 0.f, 0.f}, vb = {0.f, 0.f, 0.f, 0.f};
        if (row0 + r < n) {
            va = *(const float4*)&Xf[(size_t)(row0 + r) * D + kc];
            vb = *(const float4*)&Xf[(size_t)(row0 + r) * D + kc + 4];
        }
        ushort4 o0, o1;
        o0.x = f2bf(va.x); o0.y = f2bf(va.y); o0.z = f2bf(va.z); o0.w = f2bf(va.w);
        o1.x = f2bf(vb.x); o1.y = f2bf(vb.y); o1.z = f2bf(vb.z); o1.w = f2bf(vb.w);
        *(ushort4*)&Xs[r * 136 + kc] = o0;
        *(ushort4*)&Xs[r * 136 + kc + 4] = o1;
    }
#pragma unroll
    for (int i = 0; i < 2; i++) {
        int c = tid + 1024 * i;
        int r = c >> 4;
        int kc = (c & 15) * 8;
        uint4 v = *(const uint4*)&Wt[r * D + kc];
        *(uint4*)&Ws[r * 136 + kc] = v;
    }
    __syncthreads();
    gemm_compute16(Xs, Ws, cnt, out, n, row0);
}

// ---- device agg for one node; half-0 lanes return float4 (bias+ReLU applied) ----
// R16: masked full-width gather iterations + slot-index software pipeline.
__device__ inline float4 agg_node_f(const uint2* __restrict__ hs2,
                                    const int* __restrict__ bucket,
                                    const int* __restrict__ cnt,
                                    const float* __restrict__ bias,
                                    int node, int half, int l32) {
    int dcnt = cnt[node];
    float dn = rsqrtf((float)dcnt + 1.0f);
    int m = min(dcnt, CAP);

    float p0 = 0.f, p1 = 0.f, p2 = 0.f, p3 = 0.f;
    float q0 = 0.f, q1 = 0.f, q2 = 0.f, q3 = 0.f;
    float r0 = 0.f, r1 = 0.f, r2 = 0.f, r3 = 0.f;
    float t0 = 0.f, t1 = 0.f, t2 = 0.f, t3 = 0.f;
    if (half == 0) {   // self term (pre-scaled row)
        uint2 u = hs2[(size_t)node * 32 + l32];
        float2 v0 = bf2x2(u.x), v1 = bf2x2(u.y);
        p0 = v0.x; p1 = v0.y; p2 = v1.x; p3 = v1.y;
    }

    int cnt_h = (m - half + 1) >> 1;   // edges this half processes
    const int* cp = bucket + (size_t)node * CAP + half;

    if (cnt_h > 0) {
        int niter = (cnt_h + 3) >> 2;
        // prologue: first 4 slot indices (invalid -> s0, a valid address)
        int s0 = cp[0];
        int s1 = (1 < cnt_h) ? cp[2] : s0;
        int s2 = (2 < cnt_h) ? cp[4] : s0;
        int s3 = (3 < cnt_h) ? cp[6] : s0;
        for (int it = 0; it < niter; it++) {
            int k = it * 4;
            // issue gathers for current 4 slots
            uint2 u0 = hs2[(size_t)s0 * 32 + l32];
            uint2 u1 = hs2[(size_t)s1 * 32 + l32];
            uint2 u2 = hs2[(size_t)s2 * 32 + l32];
            uint2 u3 = hs2[(size_t)s3 * 32 + l32];
            // prefetch next iteration's slots while gathers are in flight
            if (it + 1 < niter) {
                int kn = k + 4;
                int n0 = cp[2 * kn];
                s1 = (kn + 1 < cnt_h) ? cp[2 * kn + 2] : n0;
                s2 = (kn + 2 < cnt_h) ? cp[2 * kn + 4] : n0;
                s3 = (kn + 3 < cnt_h) ? cp[2 * kn + 6] : n0;
                s0 = n0;
            }
            // mask tail values to bf16-zero (uniform-per-half conditions)
            if (k + 1 >= cnt_h) { u1.x = 0u; u1.y = 0u; }
            if (k + 2 >= cnt_h) { u2.x = 0u; u2.y = 0u; }
            if (k + 3 >= cnt_h) { u3.x = 0u; u3.y = 0u; }
            float2 a0 = bf2x2(u0.x), a1 = bf2x2(u0.y);
            float2 b0 = bf2x2(u1.x), b1 = bf2x2(u1.y);
            float2 c0 = bf2x2(u2.x), c1 = bf2x2(u2.y);
            float2 d0 = bf2x2(u3.x), d1 = bf2x2(u3.y);
            p0 += a0.x; p1 += a0.y; p2 += a1.x; p3 += a1.y;
            q0 += b0.x; q1 += b0.y; q2 += b1.x; q3 += b1.y;
            r0 += c0.x; r1 += c0.y; r2 += c1.x; r3 += c1.y;
            t0 += d0.x; t1 += d0.y; t2 += d1.x; t3 += d1.y;
        }
    }
    float a0 = (p0 + q0) + (r0 + t0);
    float a1 = (p1 + q1) + (r1 + t1);
    float a2 = (p2 + q2) + (r2 + t2);
    float a3 = (p3 + q3) + (r3 + t3);
    a0 += __shfl_xor(a0, 32);
    a1 += __shfl_xor(a1, 32);
    a2 += __shfl_xor(a2, 32);
    a3 += __shfl_xor(a3, 32);

    float4 o = {0.f, 0.f, 0.f, 0.f};
    if (half == 0) {
        float4 b = *(const float4*)&bias[4 * l32];
        o.x = fmaxf(dn * a0 + b.x, 0.0f);
        o.y = fmaxf(dn * a1 + b.y, 0.0f);
        o.z = fmaxf(dn * a2 + b.z, 0.0f);
        o.w = fmaxf(dn * a3 + b.w, 0.0f);
    }
    return o;
}

// ------- FUSED agg1+GEMM2 (1024 thr): phase A — 16 waves aggregate 8 nodes -------
// ------- each into Xs (LDS); phase B — 16-wave MFMA GEMM -> g2b (distinct). -----
__global__ __launch_bounds__(1024) void k_agg_gemm(
        const uint2* __restrict__ hs2, const int* __restrict__ bucket,
        const int* __restrict__ cnt, const float* __restrict__ bias,
        const unsigned short* __restrict__ Wt, unsigned short* __restrict__ out,
        int n) {
    __shared__ unsigned short Xs[128 * 136];
    __shared__ unsigned short Ws[128 * 136];
    int tid = threadIdx.x;
    int row0 = blockIdx.x * 128;
    int w = tid >> 6;          // 0..15
    int lane = tid & 63;
    int half = lane >> 5;
    int l32 = lane & 31;

    // phase A: wave w aggregates nodes row0 + w*8 + j, j=0..7
#pragma unroll 1
    for (int j = 0; j < 8; j++) {
        int nl = w * 8 + j;
        int node = row0 + nl;
        float4 v = {0.f, 0.f, 0.f, 0.f};
        if (node < n)
            v = agg_node_f(hs2, bucket, cnt, bias, node, half, l32);
        if (half == 0) {
            ushort4 o;
            o.x = f2bf(v.x); o.y = f2bf(v.y); o.z = f2bf(v.z); o.w = f2bf(v.w);
            *(ushort4*)&Xs[nl * 136 + 4 * l32] = o;
        }
    }
    // stage Ws
#pragma unroll
    for (int i = 0; i < 2; i++) {
        int c = tid + 1024 * i;
        int r = c >> 4;
        int kc = (c & 15) * 8;
        uint4 v = *(const uint4*)&Wt[r * D + kc];
        *(uint4*)&Ws[r * 136 + kc] = v;
    }
    __syncthreads();

    // phase B: GEMM on the LDS-resident h1 tile
    gemm_compute16(Xs, Ws, cnt, out, n, row0);
}

// ---- FUSED agg2 + BN-stats (1024 thr, 512 blocks, grid-stride over nodes) ----
// Each wave handles node = blk*16 + w + iter*8192; half-0 lanes accumulate
// per-feature sum/sumsq in registers; LDS reduce across 16 waves; 256
// strided atomics per block into S.
__global__ __launch_bounds__(1024) void k_agg_stats(
        const uint2* __restrict__ hs2, const int* __restrict__ bucket,
        const int* __restrict__ cnt, const float* __restrict__ bias,
        unsigned short* __restrict__ h2, float* __restrict__ S, int N) {
    int tid = threadIdx.x;
    int w = tid >> 6;
    int lane = tid & 63;
    int half = lane >> 5;
    int l32 = lane & 31;

    float st0 = 0.f, st1 = 0.f, st2 = 0.f, st3 = 0.f;
    float sq0 = 0.f, sq1 = 0.f, sq2 = 0.f, sq3 = 0.f;

    for (int node = blockIdx.x * 16 + w; node < N; node += gridDim.x * 16) {
        float4 v = agg_node_f(hs2, bucket, cnt, bias, node, half, l32);
        if (half == 0) {
            ushort4 o;
            o.x = f2bf(v.x); o.y = f2bf(v.y); o.z = f2bf(v.z); o.w = f2bf(v.w);
            *(ushort4*)&h2[(size_t)node * D + 4 * l32] = o;
            st0 += v.x; st1 += v.y; st2 += v.z; st3 += v.w;
            sq0 += v.x * v.x; sq1 += v.y * v.y;
            sq2 += v.z * v.z; sq3 += v.w * v.w;
        }
    }

    __shared__ float sm[16][32][8];
    if (half == 0) {
        sm[w][l32][0] = st0; sm[w][l32][1] = st1;
        sm[w][l32][2] = st2; sm[w][l32][3] = st3;
        sm[w][l32][4] = sq0; sm[w][l32][5] = sq1;
        sm[w][l32][6] = sq2; sm[w][l32][7] = sq3;
    }
    __syncthreads();
    if (tid < D) {
        int f = tid;
        float s = 0.f, q = 0.f;
#pragma unroll
        for (int ww = 0; ww < 16; ww++) {
            s += sm[ww][f >> 2][f & 3];
            q += sm[ww][f >> 2][4 + (f & 3)];
        }
        atomicAdd(&S[f * 16], s);
        atomicAdd(&S[4096 + f * 16], q);
    }
}

// ---------------- BN normalize: bf16 h2 -> f32 out ----------------
__global__ void k_bn(const unsigned* __restrict__ z2, const float* __restrict__ S,
                     const float* __restrict__ gamma, const float* __restrict__ beta,
                     float* __restrict__ out, int N) {
    int i = blockIdx.x * blockDim.x + threadIdx.x;   // uint4 index (8 features)
    int total = N * (D / 8);
    if (i >= total) return;
    int c8 = (i & (D / 8 - 1)) * 8;
    uint4 u = *(const uint4*)&z2[(size_t)i * 4];
    float v[8];
    float2 t;
    t = bf2x2(u.x); v[0] = t.x; v[1] = t.y;
    t = bf2x2(u.y); v[2] = t.x; v[3] = t.y;
    t = bf2x2(u.z); v[4] = t.x; v[5] = t.y;
    t = bf2x2(u.w); v[6] = t.x; v[7] = t.y;
    float invN = 1.0f / (float)N;
    float4 o0, o1;
#pragma unroll
    for (int j = 0; j < 8; j++) {
        float s = S[(c8 + j) * 16];
        float s2 = S[4096 + (c8 + j) * 16];
        float mu = s * invN;
        float iv = rsqrtf(fmaxf(s2 * invN - mu * mu, 0.f) + 1e-5f);
        float val = gamma[c8 + j] * (v[j] - mu) * iv + beta[c8 + j];
        if (j < 4) (&o0.x)[j] = val; else (&o1.x)[j - 4] = val;
    }
    size_t base = (size_t)i * 8;
    *(float4*)&out[base] = o0;
    *(float4*)&out[base + 4] = o1;
}

static inline size_t align_up(size_t x) { return (x + 1023) & ~(size_t)1023; }

extern "C" void kernel_launch(void* const* d_in, const int* in_sizes, int n_in,
                              void* d_out, int out_size, void* d_ws, size_t ws_size,
                              hipStream_t stream) {
    const float* x     = (const float*)d_in[0];
    const int*   ei    = (const int*)d_in[1];
    const float* W1    = (const float*)d_in[2];
    const float* b1    = (const float*)d_in[3];
    const float* W2    = (const float*)d_in[4];
    const float* b2    = (const float*)d_in[5];
    const float* gamma = (const float*)d_in[6];
    const float* beta  = (const float*)d_in[7];

    int N = in_sizes[0] / D;
    int E = in_sizes[1] / 2;
    const int* row = ei;
    const int* col = ei + E;

    char* p = (char*)d_ws;
    int* cnt    = (int*)p;                 // cnt[N] ++ S[8192]: one memset
    float* S    = (float*)(cnt + N);       // strided sums/sumsq, 32KB
    p += align_up((size_t)(N + 8192) * 4);
    int* bucket = (int*)p;   p += align_up((size_t)N * CAP * 4);
    unsigned short* hsb = (unsigned short*)p; p += align_up((size_t)N * D * 2);
    unsigned short* g2b = (unsigned short*)p; p += align_up((size_t)N * D * 2);
    unsigned short* h2b = (unsigned short*)p; p += align_up((size_t)N * D * 2);
    unsigned short* Wt1 = (unsigned short*)p; p += align_up((size_t)D * D * 2);
    unsigned short* Wt2 = (unsigned short*)p; p += align_up((size_t)D * D * 2);

    int gemmBlocks = (N + 127) / 128;   // 391
    int fillBlocks = (E + 255) / 256;   // 2344

    hipMemsetAsync(cnt, 0, (size_t)(N + 8192) * 4, stream);
    k_histfill<<<fillBlocks, 256, 0, stream>>>(row, col, cnt, bucket, E,
                                               W1, W2, Wt1, Wt2);
    // layer 1 GEMM
    k_gemm1<<<gemmBlocks, 1024, 0, stream>>>(x, Wt1, cnt, hsb, N);
    // fused agg1 + layer 2 GEMM: reads hsb, writes g2b (distinct)
    k_agg_gemm<<<gemmBlocks, 1024, 0, stream>>>((const uint2*)hsb, bucket, cnt, b1,
                                                Wt2, g2b, N);
    // fused layer-2 aggregation + BN stats
    k_agg_stats<<<512, 1024, 0, stream>>>((const uint2*)g2b, bucket, cnt, b2,
                                          h2b, S, N);
    // BN normalize
    k_bn<<<(N * (D / 8) + 255) / 256, 256, 0, stream>>>((const unsigned*)h2b, S,
                                                        gamma, beta, (float*)d_out, N);
}

// Round 2
// 251.634 us; speedup vs baseline: 1.0169x; 1.0169x over previous
//
#include <hip/hip_runtime.h>

// GCN block: h1 = ReLU(Agg(x@W1)+b1); h2 = ReLU(Agg(h1@W2)+b2); out = BN(h2)
// R17: one-shot width-8 masked gather in agg_node_f (shared by k_agg_gemm and
// k_agg_stats). Mean cnt_h~6, P(cnt_h<=8)~0.9 -> ~90% of nodes become ONE
// latency step: [slot loads] -> [8 concurrent gathers] -> accumulate.
// Invalid slots alias slot0's address (L1/L2 hit, no extra HBM-side traffic),
// values are masked to bf16-zero. Replaces R15's 1-quad + serial-tail (~3
// serialized latency steps/node) and R16's non-unrollable pipelined loop
// (regressed: it only prefetched L1-hot slot indices, not the gather waits).

#define D 128
#define CAP 96   // max in-degree capacity; E/N=12 mean, Poisson tail << 96

typedef __attribute__((ext_vector_type(8))) short bf16x8;
typedef __attribute__((ext_vector_type(4))) float f32x4;

__device__ inline float2 bf2x2(unsigned u) {
    float2 r;
    r.x = __uint_as_float(u << 16);
    r.y = __uint_as_float(u & 0xffff0000u);
    return r;
}
__device__ inline unsigned short f2bf(float f) {
    unsigned u = __float_as_uint(f);
    u += 0x7fffu + ((u >> 16) & 1u);   // round-to-nearest-even
    return (unsigned short)(u >> 16);
}

// ------- fused histogram+fill: one atomic per edge; + W transpose-convert -------
__global__ void k_histfill(const int* __restrict__ row, const int* __restrict__ col,
                           int* __restrict__ cnt, int* __restrict__ bucket, int E,
                           const float* __restrict__ W1, const float* __restrict__ W2,
                           unsigned short* __restrict__ Wt1,
                           unsigned short* __restrict__ Wt2) {
    int e = blockIdx.x * blockDim.x + threadIdx.x;
    if (e < E) {
        int c = col[e];
        int slot = atomicAdd(&cnt[c], 1);
        if (slot < CAP) bucket[(size_t)c * CAP + slot] = row[e];
    }
    if (blockIdx.x < D) {
        int k = blockIdx.x;
        int t = threadIdx.x;
        if (t < D) Wt1[t * D + k] = f2bf(W1[k * D + t]);
        else       Wt2[(t - D) * D + k] = f2bf(W2[k * D + (t - D)]);
    }
}

// ------ 16-wave GEMM compute: wave w -> m-tile w>>1, n-half w&1 (4 n-tiles) ------
__device__ inline void gemm_compute16(const unsigned short* Xs, const unsigned short* Ws,
                                      const int* __restrict__ cnt,
                                      unsigned short* __restrict__ out, int n, int row0) {
    int tid = threadIdx.x;
    int w = tid >> 6;          // 0..15
    int wm = w >> 1;           // m-tile 0..7
    int wn = w & 1;            // n-half 0..1
    int lane = tid & 63;
    int m16 = lane & 15;
    int quad = lane >> 4;

    f32x4 acc[4];
#pragma unroll
    for (int u = 0; u < 4; u++) acc[u] = (f32x4){0.f, 0.f, 0.f, 0.f};

#pragma unroll
    for (int kc = 0; kc < 4; kc++) {
        bf16x8 a = *(const bf16x8*)&Xs[(wm * 16 + m16) * 136 + kc * 32 + quad * 8];
        bf16x8 b[4];
#pragma unroll
        for (int u = 0; u < 4; u++)
            b[u] = *(const bf16x8*)&Ws[((wn * 4 + u) * 16 + m16) * 136 + kc * 32 + quad * 8];
#pragma unroll
        for (int u = 0; u < 4; u++)
            acc[u] = __builtin_amdgcn_mfma_f32_16x16x32_bf16(a, b[u], acc[u], 0, 0, 0);
    }

    int rbase = row0 + wm * 16 + quad * 4;
#pragma unroll
    for (int i = 0; i < 4; i++) {
        int r = rbase + i;
        if (r < n) {
            float sc = rsqrtf((float)cnt[r] + 1.0f);
#pragma unroll
            for (int u = 0; u < 4; u++)
                out[(size_t)r * D + (wn * 4 + u) * 16 + m16] = f2bf(acc[u][i] * sc);
        }
    }
}

// -- GEMM1 (1024 thr, 16 waves): out[r] = bf16((X @ W)[r] * rsqrt(cnt[r]+1)) --
__global__ __launch_bounds__(1024) void k_gemm1(
        const float* __restrict__ Xf, const unsigned short* __restrict__ Wt,
        const int* __restrict__ cnt, unsigned short* __restrict__ out, int n) {
    __shared__ unsigned short Xs[128 * 136];   // +8 pad: 2-way banks (free)
    __shared__ unsigned short Ws[128 * 136];
    int tid = threadIdx.x;
    int row0 = blockIdx.x * 128;

#pragma unroll
    for (int i = 0; i < 2; i++) {
        int c = tid + 1024 * i;
        int r = c >> 4;
        int kc = (c & 15) * 8;
        float4 va = {0.f, 0.f, 0.f, 0.f}, vb = {0.f, 0.f, 0.f, 0.f};
        if (row0 + r < n) {
            va = *(const float4*)&Xf[(size_t)(row0 + r) * D + kc];
            vb = *(const float4*)&Xf[(size_t)(row0 + r) * D + kc + 4];
        }
        ushort4 o0, o1;
        o0.x = f2bf(va.x); o0.y = f2bf(va.y); o0.z = f2bf(va.z); o0.w = f2bf(va.w);
        o1.x = f2bf(vb.x); o1.y = f2bf(vb.y); o1.z = f2bf(vb.z); o1.w = f2bf(vb.w);
        *(ushort4*)&Xs[r * 136 + kc] = o0;
        *(ushort4*)&Xs[r * 136 + kc + 4] = o1;
    }
#pragma unroll
    for (int i = 0; i < 2; i++) {
        int c = tid + 1024 * i;
        int r = c >> 4;
        int kc = (c & 15) * 8;
        uint4 v = *(const uint4*)&Wt[r * D + kc];
        *(uint4*)&Ws[r * 136 + kc] = v;
    }
    __syncthreads();
    gemm_compute16(Xs, Ws, cnt, out, n, row0);
}

// ---- device agg for one node; half-0 lanes return float4 (bias+ReLU applied) ----
// R17: width-8 masked gather — one latency step for ~90% of nodes.
__device__ inline float4 agg_node_f(const uint2* __restrict__ hs2,
                                    const int* __restrict__ bucket,
                                    const int* __restrict__ cnt,
                                    const float* __restrict__ bias,
                                    int node, int half, int l32) {
    int dcnt = cnt[node];
    float dn = rsqrtf((float)dcnt + 1.0f);
    int m = min(dcnt, CAP);

    float p0 = 0.f, p1 = 0.f, p2 = 0.f, p3 = 0.f;
    float q0 = 0.f, q1 = 0.f, q2 = 0.f, q3 = 0.f;
    float r0 = 0.f, r1 = 0.f, r2 = 0.f, r3 = 0.f;
    float t0 = 0.f, t1 = 0.f, t2 = 0.f, t3 = 0.f;
    if (half == 0) {   // self term (pre-scaled row)
        uint2 u = hs2[(size_t)node * 32 + l32];
        float2 v0 = bf2x2(u.x), v1 = bf2x2(u.y);
        p0 = v0.x; p1 = v0.y; p2 = v1.x; p3 = v1.y;
    }

    int cnt_h = (m - half + 1) >> 1;   // edges this half processes
    const int* cp = bucket + (size_t)node * CAP + half;

    for (int k = 0; k < cnt_h; k += 8) {
        int rem = cnt_h - k;           // >= 1
        // 8 slot indices; invalid ones alias slot0 (valid addr, cache-hot)
        int s0 = cp[2 * k];
        int s1 = (1 < rem) ? cp[2 * k + 2]  : s0;
        int s2 = (2 < rem) ? cp[2 * k + 4]  : s0;
        int s3 = (3 < rem) ? cp[2 * k + 6]  : s0;
        int s4 = (4 < rem) ? cp[2 * k + 8]  : s0;
        int s5 = (5 < rem) ? cp[2 * k + 10] : s0;
        int s6 = (6 < rem) ? cp[2 * k + 12] : s0;
        int s7 = (7 < rem) ? cp[2 * k + 14] : s0;
        // 8 concurrent gathers — single vmcnt wait
        uint2 u0 = hs2[(size_t)s0 * 32 + l32];
        uint2 u1 = hs2[(size_t)s1 * 32 + l32];
        uint2 u2 = hs2[(size_t)s2 * 32 + l32];
        uint2 u3 = hs2[(size_t)s3 * 32 + l32];
        uint2 u4 = hs2[(size_t)s4 * 32 + l32];
        uint2 u5 = hs2[(size_t)s5 * 32 + l32];
        uint2 u6 = hs2[(size_t)s6 * 32 + l32];
        uint2 u7 = hs2[(size_t)s7 * 32 + l32];
        // mask tail values to bf16-zero (conditions uniform per half-wave)
        if (1 >= rem) { u1.x = 0u; u1.y = 0u; }
        if (2 >= rem) { u2.x = 0u; u2.y = 0u; }
        if (3 >= rem) { u3.x = 0u; u3.y = 0u; }
        if (4 >= rem) { u4.x = 0u; u4.y = 0u; }
        if (5 >= rem) { u5.x = 0u; u5.y = 0u; }
        if (6 >= rem) { u6.x = 0u; u6.y = 0u; }
        if (7 >= rem) { u7.x = 0u; u7.y = 0u; }
        float2 a0 = bf2x2(u0.x), a1 = bf2x2(u0.y);
        float2 b0 = bf2x2(u1.x), b1 = bf2x2(u1.y);
        float2 c0 = bf2x2(u2.x), c1 = bf2x2(u2.y);
        float2 d0 = bf2x2(u3.x), d1 = bf2x2(u3.y);
        float2 e0 = bf2x2(u4.x), e1 = bf2x2(u4.y);
        float2 f0 = bf2x2(u5.x), f1 = bf2x2(u5.y);
        float2 g0 = bf2x2(u6.x), g1 = bf2x2(u6.y);
        float2 h0 = bf2x2(u7.x), h1 = bf2x2(u7.y);
        p0 += a0.x + e0.x; p1 += a0.y + e0.y; p2 += a1.x + e1.x; p3 += a1.y + e1.y;
        q0 += b0.x + f0.x; q1 += b0.y + f0.y; q2 += b1.x + f1.x; q3 += b1.y + f1.y;
        r0 += c0.x + g0.x; r1 += c0.y + g0.y; r2 += c1.x + g1.x; r3 += c1.y + g1.y;
        t0 += d0.x + h0.x; t1 += d0.y + h0.y; t2 += d1.x + h1.x; t3 += d1.y + h1.y;
    }
    float a0 = (p0 + q0) + (r0 + t0);
    float a1 = (p1 + q1) + (r1 + t1);
    float a2 = (p2 + q2) + (r2 + t2);
    float a3 = (p3 + q3) + (r3 + t3);
    a0 += __shfl_xor(a0, 32);
    a1 += __shfl_xor(a1, 32);
    a2 += __shfl_xor(a2, 32);
    a3 += __shfl_xor(a3, 32);

    float4 o = {0.f, 0.f, 0.f, 0.f};
    if (half == 0) {
        float4 b = *(const float4*)&bias[4 * l32];
        o.x = fmaxf(dn * a0 + b.x, 0.0f);
        o.y = fmaxf(dn * a1 + b.y, 0.0f);
        o.z = fmaxf(dn * a2 + b.z, 0.0f);
        o.w = fmaxf(dn * a3 + b.w, 0.0f);
    }
    return o;
}

// ------- FUSED agg1+GEMM2 (1024 thr): phase A — 16 waves aggregate 8 nodes -------
// ------- each into Xs (LDS); phase B — 16-wave MFMA GEMM -> g2b (distinct). -----
__global__ __launch_bounds__(1024) void k_agg_gemm(
        const uint2* __restrict__ hs2, const int* __restrict__ bucket,
        const int* __restrict__ cnt, const float* __restrict__ bias,
        const unsigned short* __restrict__ Wt, unsigned short* __restrict__ out,
        int n) {
    __shared__ unsigned short Xs[128 * 136];
    __shared__ unsigned short Ws[128 * 136];
    int tid = threadIdx.x;
    int row0 = blockIdx.x * 128;
    int w = tid >> 6;          // 0..15
    int lane = tid & 63;
    int half = lane >> 5;
    int l32 = lane & 31;

    // phase A: wave w aggregates nodes row0 + w*8 + j, j=0..7
#pragma unroll 1
    for (int j = 0; j < 8; j++) {
        int nl = w * 8 + j;
        int node = row0 + nl;
        float4 v = {0.f, 0.f, 0.f, 0.f};
        if (node < n)
            v = agg_node_f(hs2, bucket, cnt, bias, node, half, l32);
        if (half == 0) {
            ushort4 o;
            o.x = f2bf(v.x); o.y = f2bf(v.y); o.z = f2bf(v.z); o.w = f2bf(v.w);
            *(ushort4*)&Xs[nl * 136 + 4 * l32] = o;
        }
    }
    // stage Ws
#pragma unroll
    for (int i = 0; i < 2; i++) {
        int c = tid + 1024 * i;
        int r = c >> 4;
        int kc = (c & 15) * 8;
        uint4 v = *(const uint4*)&Wt[r * D + kc];
        *(uint4*)&Ws[r * 136 + kc] = v;
    }
    __syncthreads();

    // phase B: GEMM on the LDS-resident h1 tile
    gemm_compute16(Xs, Ws, cnt, out, n, row0);
}

// ---- FUSED agg2 + BN-stats (1024 thr, 512 blocks, grid-stride over nodes) ----
// Each wave handles node = blk*16 + w + iter*8192; half-0 lanes accumulate
// per-feature sum/sumsq in registers; LDS reduce across 16 waves; 256
// strided atomics per block into S.
__global__ __launch_bounds__(1024) void k_agg_stats(
        const uint2* __restrict__ hs2, const int* __restrict__ bucket,
        const int* __restrict__ cnt, const float* __restrict__ bias,
        unsigned short* __restrict__ h2, float* __restrict__ S, int N) {
    int tid = threadIdx.x;
    int w = tid >> 6;
    int lane = tid & 63;
    int half = lane >> 5;
    int l32 = lane & 31;

    float st0 = 0.f, st1 = 0.f, st2 = 0.f, st3 = 0.f;
    float sq0 = 0.f, sq1 = 0.f, sq2 = 0.f, sq3 = 0.f;

    for (int node = blockIdx.x * 16 + w; node < N; node += gridDim.x * 16) {
        float4 v = agg_node_f(hs2, bucket, cnt, bias, node, half, l32);
        if (half == 0) {
            ushort4 o;
            o.x = f2bf(v.x); o.y = f2bf(v.y); o.z = f2bf(v.z); o.w = f2bf(v.w);
            *(ushort4*)&h2[(size_t)node * D + 4 * l32] = o;
            st0 += v.x; st1 += v.y; st2 += v.z; st3 += v.w;
            sq0 += v.x * v.x; sq1 += v.y * v.y;
            sq2 += v.z * v.z; sq3 += v.w * v.w;
        }
    }

    __shared__ float sm[16][32][8];
    if (half == 0) {
        sm[w][l32][0] = st0; sm[w][l32][1] = st1;
        sm[w][l32][2] = st2; sm[w][l32][3] = st3;
        sm[w][l32][4] = sq0; sm[w][l32][5] = sq1;
        sm[w][l32][6] = sq2; sm[w][l32][7] = sq3;
    }
    __syncthreads();
    if (tid < D) {
        int f = tid;
        float s = 0.f, q = 0.f;
#pragma unroll
        for (int ww = 0; ww < 16; ww++) {
            s += sm[ww][f >> 2][f & 3];
            q += sm[ww][f >> 2][4 + (f & 3)];
        }
        atomicAdd(&S[f * 16], s);
        atomicAdd(&S[4096 + f * 16], q);
    }
}

// ---------------- BN normalize: bf16 h2 -> f32 out ----------------
__global__ void k_bn(const unsigned* __restrict__ z2, const float* __restrict__ S,
                     const float* __restrict__ gamma, const float* __restrict__ beta,
                     float* __restrict__ out, int N) {
    int i = blockIdx.x * blockDim.x + threadIdx.x;   // uint4 index (8 features)
    int total = N * (D / 8);
    if (i >= total) return;
    int c8 = (i & (D / 8 - 1)) * 8;
    uint4 u = *(const uint4*)&z2[(size_t)i * 4];
    float v[8];
    float2 t;
    t = bf2x2(u.x); v[0] = t.x; v[1] = t.y;
    t = bf2x2(u.y); v[2] = t.x; v[3] = t.y;
    t = bf2x2(u.z); v[4] = t.x; v[5] = t.y;
    t = bf2x2(u.w); v[6] = t.x; v[7] = t.y;
    float invN = 1.0f / (float)N;
    float4 o0, o1;
#pragma unroll
    for (int j = 0; j < 8; j++) {
        float s = S[(c8 + j) * 16];
        float s2 = S[4096 + (c8 + j) * 16];
        float mu = s * invN;
        float iv = rsqrtf(fmaxf(s2 * invN - mu * mu, 0.f) + 1e-5f);
        float val = gamma[c8 + j] * (v[j] - mu) * iv + beta[c8 + j];
        if (j < 4) (&o0.x)[j] = val; else (&o1.x)[j - 4] = val;
    }
    size_t base = (size_t)i * 8;
    *(float4*)&out[base] = o0;
    *(float4*)&out[base + 4] = o1;
}

static inline size_t align_up(size_t x) { return (x + 1023) & ~(size_t)1023; }

extern "C" void kernel_launch(void* const* d_in, const int* in_sizes, int n_in,
                              void* d_out, int out_size, void* d_ws, size_t ws_size,
                              hipStream_t stream) {
    const float* x     = (const float*)d_in[0];
    const int*   ei    = (const int*)d_in[1];
    const float* W1    = (const float*)d_in[2];
    const float* b1    = (const float*)d_in[3];
    const float* W2    = (const float*)d_in[4];
    const float* b2    = (const float*)d_in[5];
    const float* gamma = (const float*)d_in[6];
    const float* beta  = (const float*)d_in[7];

    int N = in_sizes[0] / D;
    int E = in_sizes[1] / 2;
    const int* row = ei;
    const int* col = ei + E;

    char* p = (char*)d_ws;
    int* cnt    = (int*)p;                 // cnt[N] ++ S[8192]: one memset
    float* S    = (float*)(cnt + N);       // strided sums/sumsq, 32KB
    p += align_up((size_t)(N + 8192) * 4);
    int* bucket = (int*)p;   p += align_up((size_t)N * CAP * 4);
    unsigned short* hsb = (unsigned short*)p; p += align_up((size_t)N * D * 2);
    unsigned short* g2b = (unsigned short*)p; p += align_up((size_t)N * D * 2);
    unsigned short* h2b = (unsigned short*)p; p += align_up((size_t)N * D * 2);
    unsigned short* Wt1 = (unsigned short*)p; p += align_up((size_t)D * D * 2);
    unsigned short* Wt2 = (unsigned short*)p; p += align_up((size_t)D * D * 2);

    int gemmBlocks = (N + 127) / 128;   // 391
    int fillBlocks = (E + 255) / 256;   // 2344

    hipMemsetAsync(cnt, 0, (size_t)(N + 8192) * 4, stream);
    k_histfill<<<fillBlocks, 256, 0, stream>>>(row, col, cnt, bucket, E,
                                               W1, W2, Wt1, Wt2);
    // layer 1 GEMM
    k_gemm1<<<gemmBlocks, 1024, 0, stream>>>(x, Wt1, cnt, hsb, N);
    // fused agg1 + layer 2 GEMM: reads hsb, writes g2b (distinct)
    k_agg_gemm<<<gemmBlocks, 1024, 0, stream>>>((const uint2*)hsb, bucket, cnt, b1,
                                                Wt2, g2b, N);
    // fused layer-2 aggregation + BN stats
    k_agg_stats<<<512, 1024, 0, stream>>>((const uint2*)g2b, bucket, cnt, b2,
                                          h2b, S, N);
    // BN normalize
    k_bn<<<(N * (D / 8) + 255) / 256, 256, 0, stream>>>((const unsigned*)h2b, S,
                                                        gamma, beta, (float*)d_out, N);
}

// Round 3
// 233.242 us; speedup vs baseline: 1.0970x; 1.0789x over previous
//
#include <hip/hip_runtime.h>

// GCN block: h1 = ReLU(Agg(x@W1)+b1); h2 = ReLU(Agg(h1@W2)+b2); out = BN(h2)
// R18: the gather is latency-bound and the compiler serialized it (R17's
// VGPR=36 proves <=2 gathers in flight). Force MLP=8 with an inline-asm
// gather block (8x global_load_dwordx2, =&v early-clobber, one
// s_waitcnt vmcnt(0) + sched_barrier(0) per the m214 r263/r282 rule).
// Bucket layout split per half (slot s -> half s&1, idx s>>1) so each
// half-wave's 8 slot indices arrive in two int4 loads; next node's slots
// and cnt are prefetched before the current node's gather wait (their
// latency hides under the gathers). Same edge order per half as R17 ->
// identical numerics.

#define D 128
#define CAP 96   // max in-degree capacity; E/N=12 mean, Poisson tail << 96

typedef __attribute__((ext_vector_type(8))) short bf16x8;
typedef __attribute__((ext_vector_type(4))) float f32x4;
typedef __attribute__((ext_vector_type(2))) unsigned u32x2;

__device__ inline float2 bf2x2(unsigned u) {
    float2 r;
    r.x = __uint_as_float(u << 16);
    r.y = __uint_as_float(u & 0xffff0000u);
    return r;
}
__device__ inline unsigned short f2bf(float f) {
    unsigned u = __float_as_uint(f);
    u += 0x7fffu + ((u >> 16) & 1u);   // round-to-nearest-even
    return (unsigned short)(u >> 16);
}

// ------- fused histogram+fill: one atomic per edge; + W transpose-convert -------
// R18: split-half bucket layout — half h slots contiguous at [c*CAP + h*48 ..].
__global__ void k_histfill(const int* __restrict__ row, const int* __restrict__ col,
                           int* __restrict__ cnt, int* __restrict__ bucket, int E,
                           const float* __restrict__ W1, const float* __restrict__ W2,
                           unsigned short* __restrict__ Wt1,
                           unsigned short* __restrict__ Wt2) {
    int e = blockIdx.x * blockDim.x + threadIdx.x;
    if (e < E) {
        int c = col[e];
        int slot = atomicAdd(&cnt[c], 1);
        if (slot < CAP)
            bucket[(size_t)c * CAP + (slot & 1) * (CAP / 2) + (slot >> 1)] = row[e];
    }
    if (blockIdx.x < D) {
        int k = blockIdx.x;
        int t = threadIdx.x;
        if (t < D) Wt1[t * D + k] = f2bf(W1[k * D + t]);
        else       Wt2[(t - D) * D + k] = f2bf(W2[k * D + (t - D)]);
    }
}

// ------ 16-wave GEMM compute: wave w -> m-tile w>>1, n-half w&1 (4 n-tiles) ------
__device__ inline void gemm_compute16(const unsigned short* Xs, const unsigned short* Ws,
                                      const int* __restrict__ cnt,
                                      unsigned short* __restrict__ out, int n, int row0) {
    int tid = threadIdx.x;
    int w = tid >> 6;          // 0..15
    int wm = w >> 1;           // m-tile 0..7
    int wn = w & 1;            // n-half 0..1
    int lane = tid & 63;
    int m16 = lane & 15;
    int quad = lane >> 4;

    f32x4 acc[4];
#pragma unroll
    for (int u = 0; u < 4; u++) acc[u] = (f32x4){0.f, 0.f, 0.f, 0.f};

#pragma unroll
    for (int kc = 0; kc < 4; kc++) {
        bf16x8 a = *(const bf16x8*)&Xs[(wm * 16 + m16) * 136 + kc * 32 + quad * 8];
        bf16x8 b[4];
#pragma unroll
        for (int u = 0; u < 4; u++)
            b[u] = *(const bf16x8*)&Ws[((wn * 4 + u) * 16 + m16) * 136 + kc * 32 + quad * 8];
#pragma unroll
        for (int u = 0; u < 4; u++)
            acc[u] = __builtin_amdgcn_mfma_f32_16x16x32_bf16(a, b[u], acc[u], 0, 0, 0);
    }

    int rbase = row0 + wm * 16 + quad * 4;
#pragma unroll
    for (int i = 0; i < 4; i++) {
        int r = rbase + i;
        if (r < n) {
            float sc = rsqrtf((float)cnt[r] + 1.0f);
#pragma unroll
            for (int u = 0; u < 4; u++)
                out[(size_t)r * D + (wn * 4 + u) * 16 + m16] = f2bf(acc[u][i] * sc);
        }
    }
}

// -- GEMM1 (1024 thr, 16 waves): out[r] = bf16((X @ W)[r] * rsqrt(cnt[r]+1)) --
__global__ __launch_bounds__(1024) void k_gemm1(
        const float* __restrict__ Xf, const unsigned short* __restrict__ Wt,
        const int* __restrict__ cnt, unsigned short* __restrict__ out, int n) {
    __shared__ unsigned short Xs[128 * 136];   // +8 pad: 2-way banks (free)
    __shared__ unsigned short Ws[128 * 136];
    int tid = threadIdx.x;
    int row0 = blockIdx.x * 128;

#pragma unroll
    for (int i = 0; i < 2; i++) {
        int c = tid + 1024 * i;
        int r = c >> 4;
        int kc = (c & 15) * 8;
        float4 va = {0.f, 0.f, 0.f, 0.f}, vb = {0.f, 0.f, 0.f, 0.f};
        if (row0 + r < n) {
            va = *(const float4*)&Xf[(size_t)(row0 + r) * D + kc];
            vb = *(const float4*)&Xf[(size_t)(row0 + r) * D + kc + 4];
        }
        ushort4 o0, o1;
        o0.x = f2bf(va.x); o0.y = f2bf(va.y); o0.z = f2bf(va.z); o0.w = f2bf(va.w);
        o1.x = f2bf(vb.x); o1.y = f2bf(vb.y); o1.z = f2bf(vb.z); o1.w = f2bf(vb.w);
        *(ushort4*)&Xs[r * 136 + kc] = o0;
        *(ushort4*)&Xs[r * 136 + kc + 4] = o1;
    }
#pragma unroll
    for (int i = 0; i < 2; i++) {
        int c = tid + 1024 * i;
        int r = c >> 4;
        int kc = (c & 15) * 8;
        uint4 v = *(const uint4*)&Wt[r * D + kc];
        *(uint4*)&Ws[r * 136 + kc] = v;
    }
    __syncthreads();
    gemm_compute16(Xs, Ws, cnt, out, n, row0);
}

// ---- 8-wide forced-MLP gather: 8 concurrent row gathers, one vmcnt wait ----
__device__ inline void gather8(const char* bp, int4 sa, int4 sb, int rem,
                               f32x4& P, f32x4& Q, f32x4& R, f32x4& T) {
    // sanitize slot indices (garbage beyond rem) -> alias s0 (valid, cache-hot)
    int s0 = (0 < rem) ? sa.x : 0;
    int s1 = (1 < rem) ? sa.y : s0;
    int s2 = (2 < rem) ? sa.z : s0;
    int s3 = (3 < rem) ? sa.w : s0;
    int s4 = (4 < rem) ? sb.x : s0;
    int s5 = (5 < rem) ? sb.y : s0;
    int s6 = (6 < rem) ? sb.z : s0;
    int s7 = (7 < rem) ? sb.w : s0;
    u32x2 u0, u1, u2, u3, u4, u5, u6, u7;
    asm volatile(
        "global_load_dwordx2 %0, %8, off\n\t"
        "global_load_dwordx2 %1, %9, off\n\t"
        "global_load_dwordx2 %2, %10, off\n\t"
        "global_load_dwordx2 %3, %11, off\n\t"
        "global_load_dwordx2 %4, %12, off\n\t"
        "global_load_dwordx2 %5, %13, off\n\t"
        "global_load_dwordx2 %6, %14, off\n\t"
        "global_load_dwordx2 %7, %15, off"
        : "=&v"(u0), "=&v"(u1), "=&v"(u2), "=&v"(u3),
          "=&v"(u4), "=&v"(u5), "=&v"(u6), "=&v"(u7)
        : "v"(bp + ((size_t)(unsigned)s0 << 8)),
          "v"(bp + ((size_t)(unsigned)s1 << 8)),
          "v"(bp + ((size_t)(unsigned)s2 << 8)),
          "v"(bp + ((size_t)(unsigned)s3 << 8)),
          "v"(bp + ((size_t)(unsigned)s4 << 8)),
          "v"(bp + ((size_t)(unsigned)s5 << 8)),
          "v"(bp + ((size_t)(unsigned)s6 << 8)),
          "v"(bp + ((size_t)(unsigned)s7 << 8)));
    asm volatile("s_waitcnt vmcnt(0)" ::: "memory");
    __builtin_amdgcn_sched_barrier(0);   // consumers must not cross upward
    // mask tail values to bf16-zero (rem uniform per half-wave)
    if (0 >= rem) { u0[0] = 0u; u0[1] = 0u; }
    if (1 >= rem) { u1[0] = 0u; u1[1] = 0u; }
    if (2 >= rem) { u2[0] = 0u; u2[1] = 0u; }
    if (3 >= rem) { u3[0] = 0u; u3[1] = 0u; }
    if (4 >= rem) { u4[0] = 0u; u4[1] = 0u; }
    if (5 >= rem) { u5[0] = 0u; u5[1] = 0u; }
    if (6 >= rem) { u6[0] = 0u; u6[1] = 0u; }
    if (7 >= rem) { u7[0] = 0u; u7[1] = 0u; }
    float2 a0 = bf2x2(u0[0]), a1 = bf2x2(u0[1]);
    float2 b0 = bf2x2(u1[0]), b1 = bf2x2(u1[1]);
    float2 c0 = bf2x2(u2[0]), c1 = bf2x2(u2[1]);
    float2 d0 = bf2x2(u3[0]), d1 = bf2x2(u3[1]);
    float2 e0 = bf2x2(u4[0]), e1 = bf2x2(u4[1]);
    float2 f0 = bf2x2(u5[0]), f1 = bf2x2(u5[1]);
    float2 g0 = bf2x2(u6[0]), g1 = bf2x2(u6[1]);
    float2 h0 = bf2x2(u7[0]), h1 = bf2x2(u7[1]);
    P[0] += a0.x + e0.x; P[1] += a0.y + e0.y; P[2] += a1.x + e1.x; P[3] += a1.y + e1.y;
    Q[0] += b0.x + f0.x; Q[1] += b0.y + f0.y; Q[2] += b1.x + f1.x; Q[3] += b1.y + f1.y;
    R[0] += c0.x + g0.x; R[1] += c0.y + g0.y; R[2] += c1.x + g1.x; R[3] += c1.y + g1.y;
    T[0] += d0.x + h0.x; T[1] += d0.y + h0.y; T[2] += d1.x + h1.x; T[3] += d1.y + h1.y;
}

// ---- device agg for one node; half-0 lanes return float4 (bias+ReLU applied) ----
// Takes preloaded dcnt + first-8 slot indices (pipelined by the caller).
__device__ inline float4 agg_node_f(const uint2* __restrict__ hs2,
                                    const int* __restrict__ cp, int dcnt,
                                    int4 sa, int4 sb,
                                    const float* __restrict__ bias,
                                    int node, int half, int l32) {
    float dn = rsqrtf((float)dcnt + 1.0f);
    int m = min(dcnt, CAP);
    int cnt_h = (m - half + 1) >> 1;   // edges this half processes

    uint2 su = hs2[(size_t)node * 32 + l32];   // self row; consumed after gathers

    f32x4 P = {0.f, 0.f, 0.f, 0.f}, Q = P, R = P, T = P;
    const char* bp = (const char*)hs2 + (size_t)l32 * 8;
    gather8(bp, sa, sb, cnt_h, P, Q, R, T);
#pragma unroll 1
    for (int k = 8; k < cnt_h; k += 8) {       // rare tail (deg > 16/17)
        int4 xa = *(const int4*)&cp[k];
        int4 xb = *(const int4*)&cp[k + 4];
        gather8(bp, xa, xb, cnt_h - k, P, Q, R, T);
    }
    if (half == 0) {   // self term (pre-scaled row)
        float2 v0 = bf2x2(su.x), v1 = bf2x2(su.y);
        P[0] += v0.x; P[1] += v0.y; P[2] += v1.x; P[3] += v1.y;
    }
    float a0 = (P[0] + Q[0]) + (R[0] + T[0]);
    float a1 = (P[1] + Q[1]) + (R[1] + T[1]);
    float a2 = (P[2] + Q[2]) + (R[2] + T[2]);
    float a3 = (P[3] + Q[3]) + (R[3] + T[3]);
    a0 += __shfl_xor(a0, 32);
    a1 += __shfl_xor(a1, 32);
    a2 += __shfl_xor(a2, 32);
    a3 += __shfl_xor(a3, 32);

    float4 o = {0.f, 0.f, 0.f, 0.f};
    if (half == 0) {
        float4 b = *(const float4*)&bias[4 * l32];
        o.x = fmaxf(dn * a0 + b.x, 0.0f);
        o.y = fmaxf(dn * a1 + b.y, 0.0f);
        o.z = fmaxf(dn * a2 + b.z, 0.0f);
        o.w = fmaxf(dn * a3 + b.w, 0.0f);
    }
    return o;
}

// ------- FUSED agg1+GEMM2 (1024 thr): phase A — 16 waves aggregate 8 nodes -------
// ------- each into Xs (LDS); phase B — 16-wave MFMA GEMM -> g2b (distinct). -----
__global__ __launch_bounds__(1024) void k_agg_gemm(
        const uint2* __restrict__ hs2, const int* __restrict__ bucket,
        const int* __restrict__ cnt, const float* __restrict__ bias,
        const unsigned short* __restrict__ Wt, unsigned short* __restrict__ out,
        int n) {
    __shared__ unsigned short Xs[128 * 136];
    __shared__ unsigned short Ws[128 * 136];
    int tid = threadIdx.x;
    int row0 = blockIdx.x * 128;
    int w = tid >> 6;          // 0..15
    int lane = tid & 63;
    int half = lane >> 5;
    int l32 = lane & 31;

    // phase A: wave w aggregates nodes row0 + w*8 + j, j=0..7 (slot/cnt pipelined)
    int nb = row0 + w * 8;
    const int* cp = bucket + (size_t)nb * CAP + half * (CAP / 2);
    int4 sa = *(const int4*)cp;
    int4 sb = *(const int4*)(cp + 4);
    int dcnt = cnt[min(nb, n - 1)];
#pragma unroll 1
    for (int j = 0; j < 8; j++) {
        int node = nb + j;
        // prefetch next node's slots + cnt (hides under current gathers)
        const int* cpn = cp + CAP;
        int4 sa_n = *(const int4*)cpn;
        int4 sb_n = *(const int4*)(cpn + 4);
        int dc_n = cnt[min(node + 1, n - 1)];
        float4 v = {0.f, 0.f, 0.f, 0.f};
        if (node < n)
            v = agg_node_f(hs2, cp, dcnt, sa, sb, bias, node, half, l32);
        if (half == 0) {
            ushort4 o;
            o.x = f2bf(v.x); o.y = f2bf(v.y); o.z = f2bf(v.z); o.w = f2bf(v.w);
            *(ushort4*)&Xs[(w * 8 + j) * 136 + 4 * l32] = o;
        }
        cp = cpn; sa = sa_n; sb = sb_n; dcnt = dc_n;
    }
    // stage Ws
#pragma unroll
    for (int i = 0; i < 2; i++) {
        int c = tid + 1024 * i;
        int r = c >> 4;
        int kc = (c & 15) * 8;
        uint4 v = *(const uint4*)&Wt[r * D + kc];
        *(uint4*)&Ws[r * 136 + kc] = v;
    }
    __syncthreads();

    // phase B: GEMM on the LDS-resident h1 tile
    gemm_compute16(Xs, Ws, cnt, out, n, row0);
}

// ---- FUSED agg2 + BN-stats (1024 thr, 512 blocks, grid-stride over nodes) ----
__global__ __launch_bounds__(1024) void k_agg_stats(
        const uint2* __restrict__ hs2, const int* __restrict__ bucket,
        const int* __restrict__ cnt, const float* __restrict__ bias,
        unsigned short* __restrict__ h2, float* __restrict__ S, int N) {
    int tid = threadIdx.x;
    int w = tid >> 6;
    int lane = tid & 63;
    int half = lane >> 5;
    int l32 = lane & 31;

    float st0 = 0.f, st1 = 0.f, st2 = 0.f, st3 = 0.f;
    float sq0 = 0.f, sq1 = 0.f, sq2 = 0.f, sq3 = 0.f;

    int stride = gridDim.x * 16;
    int node = blockIdx.x * 16 + w;
    int4 sa = {0, 0, 0, 0}, sb = {0, 0, 0, 0};
    int dcnt = 0;
    if (node < N) {
        const int* cp0 = bucket + (size_t)node * CAP + half * (CAP / 2);
        sa = *(const int4*)cp0;
        sb = *(const int4*)(cp0 + 4);
        dcnt = cnt[node];
    }
    for (; node < N; node += stride) {
        // prefetch next grid-stride node's slots + cnt
        int nclamp = min(node + stride, N - 1);
        const int* cpn = bucket + (size_t)nclamp * CAP + half * (CAP / 2);
        int4 sa_n = *(const int4*)cpn;
        int4 sb_n = *(const int4*)(cpn + 4);
        int dc_n = cnt[nclamp];
        const int* cp = bucket + (size_t)node * CAP + half * (CAP / 2);
        float4 v = agg_node_f(hs2, cp, dcnt, sa, sb, bias, node, half, l32);
        if (half == 0) {
            ushort4 o;
            o.x = f2bf(v.x); o.y = f2bf(v.y); o.z = f2bf(v.z); o.w = f2bf(v.w);
            *(ushort4*)&h2[(size_t)node * D + 4 * l32] = o;
            st0 += v.x; st1 += v.y; st2 += v.z; st3 += v.w;
            sq0 += v.x * v.x; sq1 += v.y * v.y;
            sq2 += v.z * v.z; sq3 += v.w * v.w;
        }
        sa = sa_n; sb = sb_n; dcnt = dc_n;
    }

    __shared__ float sm[16][32][8];
    if (half == 0) {
        sm[w][l32][0] = st0; sm[w][l32][1] = st1;
        sm[w][l32][2] = st2; sm[w][l32][3] = st3;
        sm[w][l32][4] = sq0; sm[w][l32][5] = sq1;
        sm[w][l32][6] = sq2; sm[w][l32][7] = sq3;
    }
    __syncthreads();
    if (tid < D) {
        int f = tid;
        float s = 0.f, q = 0.f;
#pragma unroll
        for (int ww = 0; ww < 16; ww++) {
            s += sm[ww][f >> 2][f & 3];
            q += sm[ww][f >> 2][4 + (f & 3)];
        }
        atomicAdd(&S[f * 16], s);
        atomicAdd(&S[4096 + f * 16], q);
    }
}

// ---------------- BN normalize: bf16 h2 -> f32 out ----------------
__global__ void k_bn(const unsigned* __restrict__ z2, const float* __restrict__ S,
                     const float* __restrict__ gamma, const float* __restrict__ beta,
                     float* __restrict__ out, int N) {
    int i = blockIdx.x * blockDim.x + threadIdx.x;   // uint4 index (8 features)
    int total = N * (D / 8);
    if (i >= total) return;
    int c8 = (i & (D / 8 - 1)) * 8;
    uint4 u = *(const uint4*)&z2[(size_t)i * 4];
    float v[8];
    float2 t;
    t = bf2x2(u.x); v[0] = t.x; v[1] = t.y;
    t = bf2x2(u.y); v[2] = t.x; v[3] = t.y;
    t = bf2x2(u.z); v[4] = t.x; v[5] = t.y;
    t = bf2x2(u.w); v[6] = t.x; v[7] = t.y;
    float invN = 1.0f / (float)N;
    float4 o0, o1;
#pragma unroll
    for (int j = 0; j < 8; j++) {
        float s = S[(c8 + j) * 16];
        float s2 = S[4096 + (c8 + j) * 16];
        float mu = s * invN;
        float iv = rsqrtf(fmaxf(s2 * invN - mu * mu, 0.f) + 1e-5f);
        float val = gamma[c8 + j] * (v[j] - mu) * iv + beta[c8 + j];
        if (j < 4) (&o0.x)[j] = val; else (&o1.x)[j - 4] = val;
    }
    size_t base = (size_t)i * 8;
    *(float4*)&out[base] = o0;
    *(float4*)&out[base + 4] = o1;
}

static inline size_t align_up(size_t x) { return (x + 1023) & ~(size_t)1023; }

extern "C" void kernel_launch(void* const* d_in, const int* in_sizes, int n_in,
                              void* d_out, int out_size, void* d_ws, size_t ws_size,
                              hipStream_t stream) {
    const float* x     = (const float*)d_in[0];
    const int*   ei    = (const int*)d_in[1];
    const float* W1    = (const float*)d_in[2];
    const float* b1    = (const float*)d_in[3];
    const float* W2    = (const float*)d_in[4];
    const float* b2    = (const float*)d_in[5];
    const float* gamma = (const float*)d_in[6];
    const float* beta  = (const float*)d_in[7];

    int N = in_sizes[0] / D;
    int E = in_sizes[1] / 2;
    const int* row = ei;
    const int* col = ei + E;

    char* p = (char*)d_ws;
    int* cnt    = (int*)p;                 // cnt[N] ++ S[8192]: one memset
    float* S    = (float*)(cnt + N);       // strided sums/sumsq, 32KB
    p += align_up((size_t)(N + 8192) * 4);
    int* bucket = (int*)p;   p += align_up((size_t)N * CAP * 4);
    unsigned short* hsb = (unsigned short*)p; p += align_up((size_t)N * D * 2);
    unsigned short* g2b = (unsigned short*)p; p += align_up((size_t)N * D * 2);
    unsigned short* h2b = (unsigned short*)p; p += align_up((size_t)N * D * 2);
    unsigned short* Wt1 = (unsigned short*)p; p += align_up((size_t)D * D * 2);
    unsigned short* Wt2 = (unsigned short*)p; p += align_up((size_t)D * D * 2);

    int gemmBlocks = (N + 127) / 128;   // 391
    int fillBlocks = (E + 255) / 256;   // 2344

    hipMemsetAsync(cnt, 0, (size_t)(N + 8192) * 4, stream);
    k_histfill<<<fillBlocks, 256, 0, stream>>>(row, col, cnt, bucket, E,
                                               W1, W2, Wt1, Wt2);
    // layer 1 GEMM
    k_gemm1<<<gemmBlocks, 1024, 0, stream>>>(x, Wt1, cnt, hsb, N);
    // fused agg1 + layer 2 GEMM: reads hsb, writes g2b (distinct)
    k_agg_gemm<<<gemmBlocks, 1024, 0, stream>>>((const uint2*)hsb, bucket, cnt, b1,
                                                Wt2, g2b, N);
    // fused layer-2 aggregation + BN stats
    k_agg_stats<<<512, 1024, 0, stream>>>((const uint2*)g2b, bucket, cnt, b2,
                                          h2b, S, N);
    // BN normalize
    k_bn<<<(N * (D / 8) + 255) / 256, 256, 0, stream>>>((const unsigned*)h2b, S,
                                                        gamma, beta, (float*)d_out, N);
}